// Round 1
// baseline (961.382 us; speedup 1.0000x reference)
//
#include <hip/hip_runtime.h>
#include <hip/hip_bf16.h>
#include <math.h>

#define DIM 100
#define BN_EPS 1e-5f

// ---------------- degree count (atomics) ----------------
__global__ void k_deg(const int* __restrict__ rows, float* __restrict__ deg, int E) {
    int i = blockIdx.x * blockDim.x + threadIdx.x;
    int stride = gridDim.x * blockDim.x;
    for (; i < E; i += stride) atomicAdd(&deg[rows[i]], 1.0f);
}

// deg -> deg_inv in place (counts are >=1 when >0)
__global__ void k_deginv(float* __restrict__ deg, int n) {
    int i = blockIdx.x * blockDim.x + threadIdx.x;
    if (i < n) { float d = deg[i]; deg[i] = d > 0.f ? rsqrtf(d) : 0.f; }
}

// ---------------- edge aggregation: agg[row] += norm * x[col] * rel[type] ----------------
__global__ void k_agg_half(const int* __restrict__ rows, const int* __restrict__ cols,
                           const int* __restrict__ types,
                           const float* __restrict__ x, const float* __restrict__ rel,
                           const float* __restrict__ dinv, float* __restrict__ agg, int E) {
    int i = blockIdx.x * blockDim.x + threadIdx.x;
    int stride = gridDim.x * blockDim.x;
    int total = E * DIM;
    for (; i < total; i += stride) {
        int e = i / DIM;
        int d = i - e * DIM;
        int r = rows[e], c = cols[e];
        float norm = dinv[r] * dinv[c];
        if (norm != 0.f) {
            int t = types[e];
            float v = x[c * DIM + d] * rel[t * DIM + d] * norm;
            atomicAdd(&agg[r * DIM + d], v);
        }
    }
}

// ---------------- fused 3-way GEMM: v = agg_in@w_in + agg_out@w_out + (x.*loop_rel)@w_loop ----------------
__global__ void k_gemm3(const float* __restrict__ agg_in, const float* __restrict__ agg_out,
                        const float* __restrict__ x, const float* __restrict__ loop_rel,
                        const float* __restrict__ w_in, const float* __restrict__ w_out,
                        const float* __restrict__ w_loop, float* __restrict__ out, int NE) {
    int i = blockIdx.x * blockDim.x + threadIdx.x;
    int total = NE * DIM;
    if (i >= total) return;
    int r = i / DIM;
    int d = i - r * DIM;
    const float* a1 = agg_in + r * DIM;
    const float* a2 = agg_out + r * DIM;
    const float* a3 = x + r * DIM;
    float acc = 0.f;
#pragma unroll 4
    for (int k = 0; k < DIM; ++k) {
        acc += a1[k] * w_in[k * DIM + d];
        acc += a2[k] * w_out[k * DIM + d];
        acc += (a3[k] * loop_rel[k]) * w_loop[k * DIM + d];
    }
    out[i] = acc;  // raw v; /3 + bias folded into BN
}

// single-matrix GEMM with optional per-k multiplier and accumulate (fallback path)
__global__ void k_gemm1(const float* __restrict__ A, const float* __restrict__ mul,
                        const float* __restrict__ W, float* __restrict__ out,
                        int NE, int accumulate) {
    int i = blockIdx.x * blockDim.x + threadIdx.x;
    int total = NE * DIM;
    if (i >= total) return;
    int r = i / DIM;
    int d = i - r * DIM;
    const float* a = A + r * DIM;
    float acc = accumulate ? out[i] : 0.f;
#pragma unroll 4
    for (int k = 0; k < DIM; ++k) {
        float m = mul ? mul[k] : 1.f;
        acc += (a[k] * m) * W[k * DIM + d];
    }
    out[i] = acc;
}

// ---------------- column stats over v (LDS partials + global atomics) ----------------
__global__ void k_stats(const float* __restrict__ v, float* __restrict__ colsum,
                        float* __restrict__ colsumsq, int total) {
    __shared__ float s[DIM], sq[DIM];
    for (int t = threadIdx.x; t < DIM; t += blockDim.x) { s[t] = 0.f; sq[t] = 0.f; }
    __syncthreads();
    int i = blockIdx.x * blockDim.x + threadIdx.x;
    int stride = gridDim.x * blockDim.x;
    for (; i < total; i += stride) {
        float val = v[i];
        int d = i % DIM;
        atomicAdd(&s[d], val);
        atomicAdd(&sq[d], val * val);
    }
    __syncthreads();
    for (int t = threadIdx.x; t < DIM; t += blockDim.x) {
        atomicAdd(&colsum[t], s[t]);
        atomicAdd(&colsumsq[t], sq[t]);
    }
}

// stats of raw v -> affine S,T so that out = tanh(v*S[d] + T[d])
__global__ void k_finalize(const float* __restrict__ colsum, const float* __restrict__ colsumsq,
                           const float* __restrict__ gamma, const float* __restrict__ beta,
                           float* __restrict__ S, float* __restrict__ T, int NE) {
    int d = threadIdx.x;
    if (d < DIM) {
        float n = (float)NE;
        float mu = colsum[d] / n;
        float ex2 = colsumsq[d] / n;
        float var = ex2 - mu * mu;
        if (var < 0.f) var = 0.f;
        // ref: out_pre = v/3 + bias; BN removes bias, var scales by 1/9
        float s = rsqrtf(var * (1.0f / 9.0f) + BN_EPS) * (1.0f / 3.0f) * gamma[d];
        S[d] = s;
        T[d] = beta[d] - mu * s;
    }
}

__global__ void k_bn_tanh(float* __restrict__ v, const float* __restrict__ S,
                          const float* __restrict__ T, int total) {
    int i = blockIdx.x * blockDim.x + threadIdx.x;
    if (i < total) {
        int d = i % DIM;
        v[i] = tanhf(v[i] * S[d] + T[d]);
    }
}

// rel_out = rel_embed @ w_rel  (rel_all[:-1] rows are exactly rel_embed)
__global__ void k_relmm(const float* __restrict__ rel, const float* __restrict__ w_rel,
                        float* __restrict__ out2, int total) {
    int i = blockIdx.x * blockDim.x + threadIdx.x;
    if (i >= total) return;
    int r = i / DIM;
    int d = i - r * DIM;
    const float* a = rel + r * DIM;
    float acc = 0.f;
#pragma unroll 4
    for (int k = 0; k < DIM; ++k) acc += a[k] * w_rel[k * DIM + d];
    out2[i] = acc;
}

extern "C" void kernel_launch(void* const* d_in, const int* in_sizes, int n_in,
                              void* d_out, int out_size, void* d_ws, size_t ws_size,
                              hipStream_t stream) {
    const float* x        = (const float*)d_in[0];
    const int*   ei       = (const int*)d_in[1];   // (2, 2E) row-major
    const int*   et       = (const int*)d_in[2];   // (2E,)
    const float* rel      = (const float*)d_in[3]; // (400,100)
    const float* w_in     = (const float*)d_in[4];
    const float* w_out    = (const float*)d_in[5];
    const float* w_loop   = (const float*)d_in[6];
    const float* w_rel    = (const float*)d_in[7];
    const float* loop_rel = (const float*)d_in[8];
    // d_in[9] = bias: cancels under BN
    const float* gamma    = (const float*)d_in[10];
    const float* beta     = (const float*)d_in[11];

    const int NE = in_sizes[0] / DIM;     // 50000
    const int E  = in_sizes[2] / 2;       // 500000
    const int twoE = 2 * E;

    float* out  = (float*)d_out;                 // (NE,DIM) tanh output
    float* out2 = out + (size_t)NE * DIM;        // (400,DIM) rel output
    const int relRows = (in_sizes[3] / DIM);     // 400

    float* ws = (float*)d_ws;
    const size_t aggElems = (size_t)NE * DIM;
    const size_t needA = (2 * aggElems + 2 * (size_t)NE + 512) * sizeof(float);

    const int B = 256;

    if (ws_size >= needA) {
        // ---- two-buffer path ----
        float* agg_in   = ws;
        float* agg_out  = agg_in + aggElems;
        float* deg_in   = agg_out + aggElems;   // 2*NE floats (in then out)
        float* deg_out  = deg_in + NE;
        float* colsum   = deg_in + 2 * (size_t)NE;
        float* colsumsq = colsum + 128;
        float* Sv       = colsumsq + 128;
        float* Tv       = Sv + 128;

        size_t zeroBytes = (2 * aggElems + 2 * (size_t)NE + 256) * sizeof(float);
        hipMemsetAsync(ws, 0, zeroBytes, stream);

        k_deg<<<1024, B, 0, stream>>>(ei, deg_in, E);            // in rows: ei[0..E)
        k_deg<<<1024, B, 0, stream>>>(ei + E, deg_out, E);       // out rows: ei[E..2E)
        k_deginv<<<(2 * NE + B - 1) / B, B, 0, stream>>>(deg_in, 2 * NE);

        k_agg_half<<<4096, B, 0, stream>>>(ei, ei + twoE, et, x, rel, deg_in, agg_in, E);
        k_agg_half<<<4096, B, 0, stream>>>(ei + E, ei + twoE + E, et + E, x, rel, deg_out, agg_out, E);

        int totalV = NE * DIM;
        k_gemm3<<<(totalV + B - 1) / B, B, 0, stream>>>(agg_in, agg_out, x, loop_rel,
                                                        w_in, w_out, w_loop, out, NE);

        k_stats<<<1024, B, 0, stream>>>(out, colsum, colsumsq, totalV);
        k_finalize<<<1, 128, 0, stream>>>(colsum, colsumsq, gamma, beta, Sv, Tv, NE);
        k_bn_tanh<<<(totalV + B - 1) / B, B, 0, stream>>>(out, Sv, Tv, totalV);

        k_relmm<<<(relRows * DIM + B - 1) / B, B, 0, stream>>>(rel, w_rel, out2, relRows * DIM);
    } else {
        // ---- one-buffer fallback ----
        float* agg      = ws;
        float* deg_in   = agg + aggElems;
        float* deg_out  = deg_in + NE;
        float* colsum   = deg_in + 2 * (size_t)NE;
        float* colsumsq = colsum + 128;
        float* Sv       = colsumsq + 128;
        float* Tv       = Sv + 128;

        size_t zeroBytes = (aggElems + 2 * (size_t)NE + 256) * sizeof(float);
        hipMemsetAsync(ws, 0, zeroBytes, stream);

        k_deg<<<1024, B, 0, stream>>>(ei, deg_in, E);
        k_deg<<<1024, B, 0, stream>>>(ei + E, deg_out, E);
        k_deginv<<<(2 * NE + B - 1) / B, B, 0, stream>>>(deg_in, 2 * NE);

        int totalV = NE * DIM;
        k_agg_half<<<4096, B, 0, stream>>>(ei, ei + twoE, et, x, rel, deg_in, agg, E);
        k_gemm1<<<(totalV + B - 1) / B, B, 0, stream>>>(agg, nullptr, w_in, out, NE, 0);

        hipMemsetAsync(agg, 0, aggElems * sizeof(float), stream);
        k_agg_half<<<4096, B, 0, stream>>>(ei + E, ei + twoE + E, et + E, x, rel, deg_out, agg, E);
        k_gemm1<<<(totalV + B - 1) / B, B, 0, stream>>>(agg, nullptr, w_out, out, NE, 1);

        k_gemm1<<<(totalV + B - 1) / B, B, 0, stream>>>(x, loop_rel, w_loop, out, NE, 1);

        k_stats<<<1024, B, 0, stream>>>(out, colsum, colsumsq, totalV);
        k_finalize<<<1, 128, 0, stream>>>(colsum, colsumsq, gamma, beta, Sv, Tv, NE);
        k_bn_tanh<<<(totalV + B - 1) / B, B, 0, stream>>>(out, Sv, Tv, totalV);

        k_relmm<<<(relRows * DIM + B - 1) / B, B, 0, stream>>>(rel, w_rel, out2, relRows * DIM);
    }
}